// Round 1
// baseline (879.092 us; speedup 1.0000x reference)
//
#include <hip/hip_runtime.h>
#include <math.h>

// ArcFace loss, N=2048 rows, C=85742 cols, fp32 in, scalar fp32 out.
//
// Per row: loss_i = logsumexp_j(logits) - logits[target]
// where logits = 32*cos everywhere except the target column, which gets the
// margin value 32*phi.  Only ONE column differs, so we stream the plain
// 32*cos logsumexp and patch the target column afterwards:
//   s     = sum_j 2^(K*(c_j - 1))          (K = 32*log2(e); factor 2^K out)
//   s_mod = s - 2^(K*(c_t-1)) + 2^(K*(phi_t-1))
//   loss  = ln2*log2(s_mod) + 32 - 32*phi_t
// Exponents lie in [-92.3, 0]: no overflow, and row max ~= 1 so s >= ~1
// (no destructive underflow).  No online max needed -> branchless hot loop.

#define NROWS 2048
#define NCOLS 85742

#define COS_M 0.8775825618903728f
#define SIN_M 0.479425538604203f
#define TH   (-0.8775825618903728f)   // cos(pi - 0.5)
#define MM    0.2397127693021015f     // sin(pi - 0.5) * 0.5
#define KLOG2 46.16624130844683f      // 32 * log2(e)
#define LN2   0.6931471805599453f

__device__ __forceinline__ float exp2_fast(float x) {
#if __has_builtin(__builtin_amdgcn_exp2f)
    return __builtin_amdgcn_exp2f(x);   // single v_exp_f32
#else
    return exp2f(x);
#endif
}

__global__ __launch_bounds__(256) void arcface_loss_kernel(
    const float* __restrict__ cosine,
    const int*   __restrict__ targets,
    float*       __restrict__ out)
{
    const int row = blockIdx.x;
    const int tid = threadIdx.x;
    const size_t base = (size_t)row * NCOLS;

    // Row pitch = 342968 B: 8-byte aligned for every row, C even ->
    // float2 loads tile the row exactly (no tail).
    const float2* __restrict__ rowp = (const float2*)(cosine + base);
    const int C2 = NCOLS / 2;   // 42871

    float s = 0.0f;
#pragma unroll 4
    for (int j = tid; j < C2; j += 256) {
        float2 v = rowp[j];
        float cx = fminf(1.0f, fmaxf(-1.0f, v.x));
        float cy = fminf(1.0f, fmaxf(-1.0f, v.y));
        s += exp2_fast(fmaf(KLOG2, cx, -KLOG2));
        s += exp2_fast(fmaf(KLOG2, cy, -KLOG2));
    }

    // Wave-64 shuffle reduction.
#pragma unroll
    for (int off = 32; off > 0; off >>= 1)
        s += __shfl_down(s, off, 64);

    __shared__ float ws[4];
    const int wave = tid >> 6;
    const int lane = tid & 63;
    if (lane == 0) ws[wave] = s;
    __syncthreads();

    if (tid == 0) {
        float st = ws[0] + ws[1] + ws[2] + ws[3];

        const int t = targets[row];
        float ct = fminf(1.0f, fmaxf(-1.0f, cosine[base + (size_t)t]));
        float sn = sqrtf(fminf(1.0f, fmaxf(0.0f, 1.0f - ct * ct)));
        float phi = ct * COS_M - sn * SIN_M;          // cos(theta + m)
        phi = (ct > TH) ? phi : (ct - MM);            // fallback branch

        // Patch the target column (same exp2(fma) form as the hot loop).
        float smod = st - exp2_fast(fmaf(KLOG2, ct,  -KLOG2))
                        + exp2_fast(fmaf(KLOG2, phi, -KLOG2));

        float loss = LN2 * log2f(smod) + 32.0f - 32.0f * phi;
        atomicAdd(out, loss * (1.0f / (float)NROWS));
    }
}

extern "C" void kernel_launch(void* const* d_in, const int* in_sizes, int n_in,
                              void* d_out, int out_size, void* d_ws, size_t ws_size,
                              hipStream_t stream) {
    const float* cosine  = (const float*)d_in[0];
    const int*   targets = (const int*)d_in[1];
    float*       out     = (float*)d_out;

    // d_out is re-poisoned to 0xAA before every timed launch; zero it on-stream
    // (async memset is graph-capture legal).
    hipMemsetAsync(out, 0, sizeof(float), stream);

    arcface_loss_kernel<<<NROWS, 256, 0, stream>>>(cosine, targets, out);
}